// Round 5
// baseline (645.137 us; speedup 1.0000x reference)
//
#include <hip/hip_runtime.h>
#include <cstdint>
#include <cstddef>

// ---------------------------------------------------------------------------
// BatchTreeEncoder on MFMA: A=4, D=7, B=64, E=128, H=128, N_NODES=5461
// Leaves (h0=0): h depends ONLY on the token ->
//   H_leaf[v][128] = full leaf GRU output per vocab entry (bf16, 12.8 MB),
//   precomputed once via MFMA (bitwise-identical to the old leaf path).
// Level-5 attention gathers child rows straight from H_leaf via tokens and
// computes the leaf max from its staged LDS tile (atomics at kernel end).
// -> level 6 costs ZERO dedicated passes over 64 MB.
// Levels 5..0: attn_mfma + persistent gru_mfma<true> (verified round-3 path).
// ---------------------------------------------------------------------------

typedef short  bf16x8 __attribute__((ext_vector_type(8)));
typedef float  f32x4  __attribute__((ext_vector_type(4)));

// workspace layout (bytes), total ~65 MB
#define WS_ACC    0u                         // 32*8192*4 = 1 MB
#define WS_WIH    1048576u                   // 384*128*2 = 96 KB
#define WS_WHH    (WS_WIH + 98304u)
#define WS_SWT    (WS_WHH + 98304u)          // 128*128*2 = 32 KB
#define WS_EMBB   (WS_SWT + 32768u)          // 50000*128*2 = 12.8 MB
#define WS_HLEAF  (WS_EMBB + 12800000u)      // 50000*128*2 = 12.8 MB
#define WS_HA     (WS_HLEAF + 12800000u)     // even levels out, max d=4: 4 MB
#define WS_HB     (WS_HA + 4194304u)         // odd levels out, max d=5: 16 MB
#define WS_H0     (WS_HB + 16777216u)        // attention out, max 16 MB

__device__ __forceinline__ float sigm(float x)   { return 1.0f / (1.0f + __expf(-x)); }
__device__ __forceinline__ float tanhf_(float x) { return 1.0f - 2.0f / (1.0f + __expf(2.0f * x)); }

__device__ __forceinline__ unsigned short f2b(float f) {
  unsigned u = __float_as_uint(f);
  u += 0x7fffu + ((u >> 16) & 1u);     // RNE (no NaN here)
  return (unsigned short)(u >> 16);
}
__device__ __forceinline__ float b2f(unsigned short s) {
  return __uint_as_float(((unsigned)s) << 16);
}

__device__ __forceinline__ unsigned fenc(float f) {
  unsigned u = __float_as_uint(f);
  return (u & 0x80000000u) ? ~u : (u | 0x80000000u);
}
__device__ __forceinline__ float fdec(unsigned e) {
  unsigned u = (e & 0x80000000u) ? (e & 0x7fffffffu) : ~e;
  return __uint_as_float(u);
}

__device__ __forceinline__ f32x4 mfma16(bf16x8 a, bf16x8 b, f32x4 c) {
  return __builtin_amdgcn_mfma_f32_16x16x32_bf16(a, b, c, 0, 0, 0);
}

__global__ __launch_bounds__(256) void decode_out(const unsigned* __restrict__ acc,
                                                  float* __restrict__ out) {
  int i = blockIdx.x * 256 + threadIdx.x;              // grid 32
  unsigned m = 0u;
  for (int s = 0; s < 32; ++s) m = max(m, acc[s * 8192 + i]);
  out[i] = fdec(m);
}

// one-shot prep: emb->bf16, weights->bf16, sent_w transpose, acc init
__global__ __launch_bounds__(256) void prep_all(const float* __restrict__ emb,
                                                const float* __restrict__ wih,
                                                const float* __restrict__ whh,
                                                const float* __restrict__ sw,
                                                unsigned short* __restrict__ embb,
                                                unsigned short* __restrict__ wihb,
                                                unsigned short* __restrict__ whhb,
                                                unsigned short* __restrict__ swtb,
                                                unsigned* __restrict__ acc) {
  size_t idx = (size_t)blockIdx.x * 256 + threadIdx.x;   // grid 7722
  if (idx < 1600000u) {                                  // 6.4M floats as float4
    float4 v = *(const float4*)(emb + idx * 4);
    ushort4 o; o.x = f2b(v.x); o.y = f2b(v.y); o.z = f2b(v.z); o.w = f2b(v.w);
    *(ushort4*)(embb + idx * 4) = o;
  } else if (idx < 1714688u) {                           // 114688 weight elems
    int i = (int)(idx - 1600000u);
    if (i < 49152)       wihb[i] = f2b(wih[i]);
    else if (i < 98304)  whhb[i - 49152] = f2b(whh[i - 49152]);
    else { int j = i - 98304; int k = j >> 7, h = j & 127; swtb[j] = f2b(sw[h * 128 + k]); }
  } else {                                               // 262144 acc words
    acc[idx - 1714688u] = 0u;
  }
}

// ---------------------------------------------------------------------------
// prep_hleaf: H_leaf[v][:] = leaf GRU output for token v.
//   gi = bf16(emb[v])·bf16(W_ih)^T (fp32 MFMA accum, identical math to the
//   old leaf x-GEMM);  r=sigm(gi_r+bR); z=sigm(gi_z+bZ);
//   n=tanh(gi_n+bN+r*bHn); h=(1-z)*n  -> bf16 (identical rounding).
// grid 782 x 512 (64 vocab rows per block). LDS-routed full-line stores.
// ---------------------------------------------------------------------------
__global__ __launch_bounds__(512, 2) void prep_hleaf(
    const unsigned short* __restrict__ embb,
    const unsigned short* __restrict__ wih,
    const float*          __restrict__ b_ih,
    const float*          __restrict__ b_hh,
    unsigned short*       __restrict__ H)
{
  __shared__ unsigned short lds[64 * 128];
  __shared__ unsigned short hvb[64 * 128];
  const int t = threadIdx.x;
  const int base = blockIdx.x * 64;

  // stage 64 sequential embb rows (XOR-swizzled 16B chunks)
#pragma unroll
  for (int i = 0; i < 2; ++i) {
    int g = t + 512 * i;
    int m = g >> 4, c = g & 15;
    int v = base + m; if (v > 49999) v = 49999;
    uint4 vv = *(const uint4*)(embb + (size_t)v * 128 + c * 8);
    *(uint4*)(lds + m * 128 + ((c ^ (m & 15)) << 3)) = vv;
  }

  const int w = __builtin_amdgcn_readfirstlane(t >> 6);
  const int lane = t & 63, l = lane & 15, q = lane >> 4;
  const int j = w * 16 + l;

  bf16x8 Br[4], Bz[4], Bn[4];
#pragma unroll
  for (int ks = 0; ks < 4; ++ks) {
    const int ko = ks * 32 + q * 8;
    Br[ks] = *(const bf16x8*)(wih + (size_t)j * 128 + ko);
    Bz[ks] = *(const bf16x8*)(wih + (size_t)(128 + j) * 128 + ko);
    Bn[ks] = *(const bf16x8*)(wih + (size_t)(256 + j) * 128 + ko);
  }
  const float bR = b_ih[j] + b_hh[j];
  const float bZ = b_ih[128 + j] + b_hh[128 + j];
  const float bN = b_ih[256 + j];
  const float bH = b_hh[256 + j];

  f32x4 Cr[4] = {{0,0,0,0},{0,0,0,0},{0,0,0,0},{0,0,0,0}};
  f32x4 Cz[4] = {{0,0,0,0},{0,0,0,0},{0,0,0,0},{0,0,0,0}};
  f32x4 Cn[4] = {{0,0,0,0},{0,0,0,0},{0,0,0,0},{0,0,0,0}};
  __syncthreads();

#pragma unroll
  for (int ks = 0; ks < 4; ++ks) {
    bf16x8 A[4];
#pragma unroll
    for (int mt = 0; mt < 4; ++mt) {
      int m = mt * 16 + l, c = ks * 4 + q;
      A[mt] = *(const bf16x8*)(lds + m * 128 + (((c ^ l) & 15) << 3));
    }
#pragma unroll
    for (int mt = 0; mt < 4; ++mt) {
      Cr[mt] = mfma16(A[mt], Br[ks], Cr[mt]);
      Cz[mt] = mfma16(A[mt], Bz[ks], Cz[mt]);
      Cn[mt] = mfma16(A[mt], Bn[ks], Cn[mt]);
    }
  }

#pragma unroll
  for (int mt = 0; mt < 4; ++mt)
#pragma unroll
    for (int e = 0; e < 4; ++e) {
      int b = mt * 16 + q * 4 + e;              // C/D: col=lane&15, row=quad*4+reg
      float r  = sigm(Cr[mt][e] + bR);
      float z  = sigm(Cz[mt][e] + bZ);
      float nv = tanhf_(Cn[mt][e] + bN + r * bH);
      float hv = (1.0f - z) * nv;
      hvb[b * 128 + (j ^ (q << 4))] = f2b(hv);
    }
  __syncthreads();

  // full-line stores
#pragma unroll
  for (int i = 0; i < 2; ++i) {
    int g = t + 512 * i;
    int b = g >> 4, c8 = (g & 15) * 8;
    int qq = (b >> 2) & 3;
    if (base + b < 50000) {
      uint4 v = *(const uint4*)(hvb + b * 128 + (c8 ^ (qq << 4)));
      *(uint4*)(H + (size_t)(base + b) * 128 + c8) = v;
    }
  }
}

// ---------------------------------------------------------------------------
// GRU (levels 5..0): persistent. Wave w owns 16 output cols j=w*16+l.
// A (x||h0) in LDS (XOR-swizzled); hv via separate hvb buffer -> uint4 stores.
// ---------------------------------------------------------------------------
template <bool HAS_H>
__global__ __launch_bounds__(512, 2) void gru_mfma(
    const int*            __restrict__ tok,
    const unsigned short* __restrict__ embb,
    const unsigned short* __restrict__ wih,
    const unsigned short* __restrict__ whh,
    const float*          __restrict__ b_ih,
    const float*          __restrict__ b_hh,
    const unsigned short* __restrict__ h0,
    unsigned short*       __restrict__ hout,
    unsigned*             __restrict__ acc,
    int nNodes, int npb)
{
  constexpr int RS  = HAS_H ? 256 : 128;   // ushorts per LDS row
  constexpr int NKS = HAS_H ? 8 : 4;
  __shared__ unsigned short lds[64 * RS];      // A tile (x || h0)
  __shared__ unsigned short hvb[64 * 128];     // hv staging for full-line store

  const int t = threadIdx.x;
  const int nodeBeg = blockIdx.x * npb;
  const int nodeEnd = min(nNodes, nodeBeg + npb);

  const int w = __builtin_amdgcn_readfirstlane(t >> 6);
  const int lane = t & 63, l = lane & 15, q = lane >> 4;
  const int j = w * 16 + l;

  // per-thread staging coords (2 chunks each for x and h0)
  const int sm0 = t >> 4,          sc0 = t & 15;          // g = t
  const int sm1 = (t + 512) >> 4,  sc1 = (t + 512) & 15;  // g = t + 512

  // B fragments in registers (rows of W are GEMM cols; frag = 8 contig k)
  bf16x8 Br[NKS], Bz[NKS], Bn[4], Bh[HAS_H ? 4 : 1];
#pragma unroll
  for (int ks = 0; ks < 4; ++ks) {
    const int ko = ks * 32 + q * 8;
    Br[ks] = *(const bf16x8*)(wih + (size_t)j * 128 + ko);
    Bz[ks] = *(const bf16x8*)(wih + (size_t)(128 + j) * 128 + ko);
    Bn[ks] = *(const bf16x8*)(wih + (size_t)(256 + j) * 128 + ko);
    if constexpr (HAS_H) {
      Br[4 + ks] = *(const bf16x8*)(whh + (size_t)j * 128 + ko);
      Bz[4 + ks] = *(const bf16x8*)(whh + (size_t)(128 + j) * 128 + ko);
      Bh[ks]     = *(const bf16x8*)(whh + (size_t)(256 + j) * 128 + ko);
    }
  }
  const float bR = b_ih[j] + b_hh[j];
  const float bZ = b_ih[128 + j] + b_hh[128 + j];
  const float bN = b_ih[256 + j];
  const float bH = b_hh[256 + j];

  float mx[4][4];
#pragma unroll
  for (int mt = 0; mt < 4; ++mt)
#pragma unroll
    for (int e = 0; e < 4; ++e) mx[mt][e] = -1e30f;

  // prefetch first node into regs
  uint4 px0, px1, ph0, ph1;
  {
    const int* tp = tok + nodeBeg * 64;
    px0 = *(const uint4*)(embb + (size_t)tp[sm0] * 128 + sc0 * 8);
    px1 = *(const uint4*)(embb + (size_t)tp[sm1] * 128 + sc1 * 8);
    if constexpr (HAS_H) {
      const unsigned short* hp = h0 + (size_t)nodeBeg * 8192;
      ph0 = *(const uint4*)(hp + sm0 * 128 + sc0 * 8);
      ph1 = *(const uint4*)(hp + sm1 * 128 + sc1 * 8);
    }
  }

  for (int node = nodeBeg; node < nodeEnd; ++node) {
    // A-write from prefetch regs (x chunks 0..15, h0 chunks 16..31)
    *(uint4*)(lds + sm0 * RS + ((sc0 ^ (sm0 & 15)) << 3)) = px0;
    *(uint4*)(lds + sm1 * RS + ((sc1 ^ (sm1 & 15)) << 3)) = px1;
    if constexpr (HAS_H) {
      *(uint4*)(lds + sm0 * 256 + ((16 | ((sc0 ^ (sm0 & 15)) & 15)) << 3)) = ph0;
      *(uint4*)(lds + sm1 * 256 + ((16 | ((sc1 ^ (sm1 & 15)) & 15)) << 3)) = ph1;
    }
    __syncthreads();

    // issue next node's loads (latency hidden under MFMA + epilogue)
    if (node + 1 < nodeEnd) {
      const int* tp = tok + (node + 1) * 64;
      px0 = *(const uint4*)(embb + (size_t)tp[sm0] * 128 + sc0 * 8);
      px1 = *(const uint4*)(embb + (size_t)tp[sm1] * 128 + sc1 * 8);
      if constexpr (HAS_H) {
        const unsigned short* hp = h0 + (size_t)(node + 1) * 8192;
        ph0 = *(const uint4*)(hp + sm0 * 128 + sc0 * 8);
        ph1 = *(const uint4*)(hp + sm1 * 128 + sc1 * 8);
      }
    }

    f32x4 Cr[4] = {{0,0,0,0},{0,0,0,0},{0,0,0,0},{0,0,0,0}};
    f32x4 Cz[4] = {{0,0,0,0},{0,0,0,0},{0,0,0,0},{0,0,0,0}};
    f32x4 Cn[4] = {{0,0,0,0},{0,0,0,0},{0,0,0,0},{0,0,0,0}};
    f32x4 Ch[4] = {{0,0,0,0},{0,0,0,0},{0,0,0,0},{0,0,0,0}};

#pragma unroll
    for (int ks = 0; ks < NKS; ++ks) {
      bf16x8 A[4];
#pragma unroll
      for (int mt = 0; mt < 4; ++mt) {
        int m = mt * 16 + l;
        int c = ks * 4 + q;
        A[mt] = *(const bf16x8*)(lds + m * RS + (((c & 16) | ((c ^ l) & 15)) << 3));
      }
#pragma unroll
      for (int mt = 0; mt < 4; ++mt) {
        Cr[mt] = mfma16(A[mt], Br[ks], Cr[mt]);
        Cz[mt] = mfma16(A[mt], Bz[ks], Cz[mt]);
        if (!HAS_H || ks < 4) Cn[mt] = mfma16(A[mt], Bn[ks & 3], Cn[mt]);
        else                  Ch[mt] = mfma16(A[mt], Bh[ks - 4], Ch[mt]);
      }
    }

    // gates in-register; hv -> hvb (q-swizzled cols); running max in regs
#pragma unroll
    for (int mt = 0; mt < 4; ++mt) {
#pragma unroll
      for (int e = 0; e < 4; ++e) {
        const int b = mt * 16 + q * 4 + e;      // C/D: col=lane&15, row=quad*4+reg
        float r  = sigm(Cr[mt][e] + bR);
        float z  = sigm(Cz[mt][e] + bZ);
        float hn_ = bH + (HAS_H ? Ch[mt][e] : 0.0f);
        float nv = tanhf_(Cn[mt][e] + bN + r * hn_);
        float hp = 0.0f;
        if constexpr (HAS_H) {
          int c16 = j >> 3;
          hp = b2f(lds[b * 256 + ((16 | ((c16 ^ (b & 15)) & 15)) << 3) + (j & 7)]);
        }
        float hv = (1.0f - z) * nv + z * hp;
        hvb[b * 128 + (j ^ (q << 4))] = f2b(hv);
        mx[mt][e] = fmaxf(mx[mt][e], hv);
      }
    }
    __syncthreads();   // A reads + hvb writes done

    // coalesced full-line hout store (reads hvb only; next A-write is disjoint)
    unsigned short* ho = hout + (size_t)node * 8192;
    {
      int b0 = sm0, c80 = sc0 * 8, q0 = (b0 >> 2) & 3;
      int b1 = sm1, c81 = sc1 * 8, q1 = (b1 >> 2) & 3;
      uint4 v0 = *(const uint4*)(hvb + b0 * 128 + (c80 ^ (q0 << 4)));
      uint4 v1 = *(const uint4*)(hvb + b1 * 128 + (c81 ^ (q1 << 4)));
      *(uint4*)(ho + b0 * 128 + c80) = v0;
      *(uint4*)(ho + b1 * 128 + c81) = v1;
    }
  }

  // one atomic set per block, at true kernel end (no barrier after)
  unsigned* accs = acc + (blockIdx.x & 31) * 8192;
#pragma unroll
  for (int mt = 0; mt < 4; ++mt)
#pragma unroll
    for (int e = 0; e < 4; ++e) {
      const int b = mt * 16 + q * 4 + e;
      atomicMax(accs + b * 128 + j, fenc(mx[mt][e]));
    }
}

// ---------------------------------------------------------------------------
// Attention: grid n (parents), block 512 (8 waves: wm=row-half, wn=col-chunk32).
// LEAF variant: child rows gathered straight from H_leaf via tokens
// (row m of parent p is token tok6[p*256+m]); also computes the leaf max
// from the staged LDS tile, atomics at true kernel end.
// ---------------------------------------------------------------------------
template <bool LEAF>
__global__ __launch_bounds__(512, 2) void attn_mfma(
    const unsigned short* __restrict__ hch,   // child h (non-leaf), rows p*256..
    const unsigned short* __restrict__ swt,   // 128x128 bf16 [k_u][h]
    const float*          __restrict__ sb,
    const float*          __restrict__ ctx,
    unsigned short*       __restrict__ h0out,
    const int*            __restrict__ tok6,  // LEAF only
    const unsigned short* __restrict__ hleaf, // LEAF only
    unsigned*             __restrict__ acc)   // LEAF only
{
  __shared__ unsigned short chs[256 * 128];   // 64 KB, swizzled
  __shared__ float spart[4][256];
  __shared__ float alf[256];

  const int p = blockIdx.x;
  const int t = threadIdx.x;

  if constexpr (LEAF) {
    const int* tokp = tok6 + p * 256;
#pragma unroll
    for (int i = 0; i < 8; ++i) {
      int g = t + 512 * i;                    // 0..4095 16B-chunks
      int m = g >> 4, c = g & 15;
      int tv = tokp[m];
      uint4 v = *(const uint4*)(hleaf + (size_t)tv * 128 + c * 8);
      *(uint4*)(chs + m * 128 + ((c ^ (m & 15)) << 3)) = v;
    }
  } else {
    const unsigned short* src = hch + (size_t)p * 256 * 128;
#pragma unroll
    for (int i = 0; i < 8; ++i) {
      int g = t + 512 * i;                    // 0..4095 16B-chunks
      int m = g >> 4, c = g & 15;
      uint4 v = *(const uint4*)(src + m * 128 + c * 8);
      *(uint4*)(chs + m * 128 + ((c ^ (m & 15)) << 3)) = v;
    }
  }

  const int w = __builtin_amdgcn_readfirstlane(t >> 6);
  const int wm = w >> 2, wn = w & 3;
  const int lane = t & 63, l = lane & 15, q = lane >> 4;

  bf16x8 Bs[2][4];
#pragma unroll
  for (int nt = 0; nt < 2; ++nt)
#pragma unroll
    for (int ks = 0; ks < 4; ++ks)
      Bs[nt][ks] = *(const bf16x8*)(swt + (size_t)(wn * 32 + nt * 16 + l) * 128 + ks * 32 + q * 8);

  f32x4 Cu[8][2] = {};
  __syncthreads();

#pragma unroll
  for (int ks = 0; ks < 4; ++ks) {
#pragma unroll
    for (int mt = 0; mt < 8; ++mt) {
      int m = wm * 128 + mt * 16 + l;
      int c = ks * 4 + q;
      bf16x8 A = *(const bf16x8*)(chs + m * 128 + (((c ^ (m & 15)) & 15) << 3));
      Cu[mt][0] = mfma16(A, Bs[0][ks], Cu[mt][0]);
      Cu[mt][1] = mfma16(A, Bs[1][ks], Cu[mt][1]);
    }
  }

  const float sb0 = sb[wn * 32 + l],  sb1 = sb[wn * 32 + 16 + l];
  const float cx0 = ctx[wn * 32 + l], cx1 = ctx[wn * 32 + 16 + l];
#pragma unroll
  for (int mt = 0; mt < 8; ++mt) {
    float pe[4];
#pragma unroll
    for (int e = 0; e < 4; ++e)
      pe[e] = tanhf_(Cu[mt][0][e] + sb0) * cx0 + tanhf_(Cu[mt][1][e] + sb1) * cx1;
#pragma unroll
    for (int mask = 1; mask < 16; mask <<= 1)
#pragma unroll
      for (int e = 0; e < 4; ++e)
        pe[e] += __shfl_xor(pe[e], mask, 16);
    if (l == 0) {
      int r = wm * 128 + mt * 16 + q * 4;
#pragma unroll
      for (int e = 0; e < 4; ++e) spart[wn][r + e] = pe[e];
    }
  }
  __syncthreads();

  if (t < 256) {
    float s = tanhf_(spart[0][t] + spart[1][t] + spart[2][t] + spart[3][t]);
    spart[0][t] = s;                          // reuse row 0 as s-values
  }
  __syncthreads();
  if (t < 64) {
    float s0 = spart[0][t], s1 = spart[0][64 + t], s2 = spart[0][128 + t], s3 = spart[0][192 + t];
    float m = fmaxf(fmaxf(s0, s1), fmaxf(s2, s3));
    float e0 = __expf(s0 - m), e1 = __expf(s1 - m), e2 = __expf(s2 - m), e3 = __expf(s3 - m);
    float inv = 1.0f / (e0 + e1 + e2 + e3);
    alf[t] = e0 * inv; alf[64 + t] = e1 * inv; alf[128 + t] = e2 * inv; alf[192 + t] = e3 * inv;
  }
  __syncthreads();

#pragma unroll
  for (int i = 0; i < 2; ++i) {
    int id = t + 512 * i;                     // 0..1023: (b, chunk)
    int b = id >> 4, c = id & 15;
    float o[8] = {0,0,0,0,0,0,0,0};
#pragma unroll
    for (int a = 0; a < 4; ++a) {
      int m = a * 64 + b;
      const unsigned short* rp = chs + m * 128 + ((c ^ (m & 15)) << 3);
      float al = alf[a * 64 + b];
#pragma unroll
      for (int k = 0; k < 8; ++k) o[k] += al * b2f(rp[k]);
    }
    ushort4 o0, o1;
    o0.x = f2b(o[0]); o0.y = f2b(o[1]); o0.z = f2b(o[2]); o0.w = f2b(o[3]);
    o1.x = f2b(o[4]); o1.y = f2b(o[5]); o1.z = f2b(o[6]); o1.w = f2b(o[7]);
    *(ushort4*)(h0out + (size_t)(p * 64 + b) * 128 + c * 8)     = o0;
    *(ushort4*)(h0out + (size_t)(p * 64 + b) * 128 + c * 8 + 4) = o1;
  }

  if constexpr (LEAF) {
    // leaf-level max from the staged tile: per (b, j), over a = 0..3
    int b = t >> 3, jb = (t & 7) * 16;
    float mxv[16];
#pragma unroll
    for (int e = 0; e < 16; ++e) mxv[e] = -1e30f;
#pragma unroll
    for (int a = 0; a < 4; ++a) {
      int m = a * 64 + b;
      const unsigned short* rp = chs + m * 128;
#pragma unroll
      for (int e = 0; e < 16; ++e) {
        int jj = jb + e, c = jj >> 3;
        float v = b2f(rp[((c ^ (m & 15)) << 3) + (jj & 7)]);
        mxv[e] = fmaxf(mxv[e], v);
      }
    }
    unsigned* accs = acc + (p & 31) * 8192 + b * 128 + jb;
#pragma unroll
    for (int e = 0; e < 16; ++e) atomicMax(accs + e, fenc(mxv[e]));
  }
}

extern "C" void kernel_launch(void* const* d_in, const int* in_sizes, int n_in,
                              void* d_out, int out_size, void* d_ws, size_t ws_size,
                              hipStream_t stream) {
  const int*   tokens = (const int*)d_in[0];
  const float* emb    = (const float*)d_in[1];
  const float* sent_w = (const float*)d_in[2];
  const float* sent_b = (const float*)d_in[3];
  const float* ctx_w  = (const float*)d_in[4];
  const float* w_ih   = (const float*)d_in[5];
  const float* w_hh   = (const float*)d_in[6];
  const float* b_ih   = (const float*)d_in[7];
  const float* b_hh   = (const float*)d_in[8];

  char* ws = (char*)d_ws;
  unsigned*       acc  = (unsigned*)(ws + WS_ACC);
  unsigned short* wihb = (unsigned short*)(ws + WS_WIH);
  unsigned short* whhb = (unsigned short*)(ws + WS_WHH);
  unsigned short* swtb = (unsigned short*)(ws + WS_SWT);
  unsigned short* embb = (unsigned short*)(ws + WS_EMBB);
  unsigned short* hlf  = (unsigned short*)(ws + WS_HLEAF);
  unsigned short* hA   = (unsigned short*)(ws + WS_HA);
  unsigned short* hB   = (unsigned short*)(ws + WS_HB);
  unsigned short* h0b  = (unsigned short*)(ws + WS_H0);

  hipLaunchKernelGGL(prep_all, dim3(7722), dim3(256), 0, stream,
                     emb, w_ih, w_hh, sent_w, embb, wihb, whhb, swtb, acc);
  hipLaunchKernelGGL(prep_hleaf, dim3(782), dim3(512), 0, stream,
                     embb, wihb, b_ih, b_hh, hlf);

  static const int offs[7] = {0, 1, 5, 21, 85, 341, 1365};
  const int* tok6 = tokens + (size_t)1365 * 64;

  for (int d = 5; d >= 0; --d) {
    int n = 1 << (2 * d);
    int off = offs[d];
    int npb  = (n + 511) / 512;                  // nodes per block
    int grid = (n + npb - 1) / npb;              // <=512, balanced chunks
    unsigned short* hout  = (d & 1) ? hB : hA;
    unsigned short* child = (d & 1) ? hA : hB;   // level d+1 output (non-leaf)
    if (d == 5) {
      hipLaunchKernelGGL((attn_mfma<true>), dim3(n), dim3(512), 0, stream,
                         (const unsigned short*)nullptr, swtb, sent_b, ctx_w,
                         h0b, tok6, hlf, acc);
    } else {
      hipLaunchKernelGGL((attn_mfma<false>), dim3(n), dim3(512), 0, stream,
                         child, swtb, sent_b, ctx_w, h0b,
                         (const int*)nullptr, (const unsigned short*)nullptr,
                         (unsigned*)nullptr);
    }
    hipLaunchKernelGGL((gru_mfma<true>), dim3(grid), dim3(512), 0, stream,
                       tokens + (size_t)off * 64, embb, wihb, whhb, b_ih, b_hh,
                       h0b, hout, acc, n, npb);
  }
  hipLaunchKernelGGL(decode_out, dim3(32), dim3(256), 0, stream, acc, (float*)d_out);
}

// Round 6
// 365.537 us; speedup vs baseline: 1.7649x; 1.7649x over previous
//
#include <hip/hip_runtime.h>
#include <cstdint>
#include <cstddef>

// ---------------------------------------------------------------------------
// BatchTreeEncoder on MFMA: A=4, D=7, B=64, E=128, H=128, N_NODES=5461
// Leaves (h0=0): h depends ONLY on the token ->
//   H_leaf[v][128] = full leaf GRU output per vocab entry (bf16, 12.8 MB),
//   precomputed once via MFMA (bitwise-identical to the old leaf path).
// Level-5 attention gathers child rows straight from H_leaf via tokens and
// computes the leaf max from its staged LDS tile. Leaf-max atomics are
// LANE-CONTIGUOUS (word = t + 512*e): coalesced RMW = 4 B/lane of fabric
// traffic (uncoalesced was 32 B/lane -> 268 MB, the round-5 regression).
// Levels 5..0: attn_mfma + persistent gru_mfma<true> (verified round-3 path).
// ---------------------------------------------------------------------------

typedef short  bf16x8 __attribute__((ext_vector_type(8)));
typedef float  f32x4  __attribute__((ext_vector_type(4)));

// workspace layout (bytes), total ~65 MB
#define WS_ACC    0u                         // 32*8192*4 = 1 MB
#define WS_WIH    1048576u                   // 384*128*2 = 96 KB
#define WS_WHH    (WS_WIH + 98304u)
#define WS_SWT    (WS_WHH + 98304u)          // 128*128*2 = 32 KB
#define WS_EMBB   (WS_SWT + 32768u)          // 50000*128*2 = 12.8 MB
#define WS_HLEAF  (WS_EMBB + 12800000u)      // 50000*128*2 = 12.8 MB
#define WS_HA     (WS_HLEAF + 12800000u)     // even levels out, max d=4: 4 MB
#define WS_HB     (WS_HA + 4194304u)         // odd levels out, max d=5: 16 MB
#define WS_H0     (WS_HB + 16777216u)        // attention out, max 16 MB

__device__ __forceinline__ float sigm(float x)   { return 1.0f / (1.0f + __expf(-x)); }
__device__ __forceinline__ float tanhf_(float x) { return 1.0f - 2.0f / (1.0f + __expf(2.0f * x)); }

__device__ __forceinline__ unsigned short f2b(float f) {
  unsigned u = __float_as_uint(f);
  u += 0x7fffu + ((u >> 16) & 1u);     // RNE (no NaN here)
  return (unsigned short)(u >> 16);
}
__device__ __forceinline__ float b2f(unsigned short s) {
  return __uint_as_float(((unsigned)s) << 16);
}

__device__ __forceinline__ unsigned fenc(float f) {
  unsigned u = __float_as_uint(f);
  return (u & 0x80000000u) ? ~u : (u | 0x80000000u);
}
__device__ __forceinline__ float fdec(unsigned e) {
  unsigned u = (e & 0x80000000u) ? (e & 0x7fffffffu) : ~e;
  return __uint_as_float(u);
}

__device__ __forceinline__ f32x4 mfma16(bf16x8 a, bf16x8 b, f32x4 c) {
  return __builtin_amdgcn_mfma_f32_16x16x32_bf16(a, b, c, 0, 0, 0);
}

__global__ __launch_bounds__(256) void decode_out(const unsigned* __restrict__ acc,
                                                  float* __restrict__ out) {
  int i = blockIdx.x * 256 + threadIdx.x;              // grid 32
  unsigned m = 0u;
  for (int s = 0; s < 32; ++s) m = max(m, acc[s * 8192 + i]);
  out[i] = fdec(m);
}

// one-shot prep: emb->bf16, weights->bf16, sent_w transpose, acc init
__global__ __launch_bounds__(256) void prep_all(const float* __restrict__ emb,
                                                const float* __restrict__ wih,
                                                const float* __restrict__ whh,
                                                const float* __restrict__ sw,
                                                unsigned short* __restrict__ embb,
                                                unsigned short* __restrict__ wihb,
                                                unsigned short* __restrict__ whhb,
                                                unsigned short* __restrict__ swtb,
                                                unsigned* __restrict__ acc) {
  size_t idx = (size_t)blockIdx.x * 256 + threadIdx.x;   // grid 7722
  if (idx < 1600000u) {                                  // 6.4M floats as float4
    float4 v = *(const float4*)(emb + idx * 4);
    ushort4 o; o.x = f2b(v.x); o.y = f2b(v.y); o.z = f2b(v.z); o.w = f2b(v.w);
    *(ushort4*)(embb + idx * 4) = o;
  } else if (idx < 1714688u) {                           // 114688 weight elems
    int i = (int)(idx - 1600000u);
    if (i < 49152)       wihb[i] = f2b(wih[i]);
    else if (i < 98304)  whhb[i - 49152] = f2b(whh[i - 49152]);
    else { int j = i - 98304; int k = j >> 7, h = j & 127; swtb[j] = f2b(sw[h * 128 + k]); }
  } else {                                               // 262144 acc words
    acc[idx - 1714688u] = 0u;
  }
}

// ---------------------------------------------------------------------------
// prep_hleaf: H_leaf[v][:] = leaf GRU output for token v.
//   gi = bf16(emb[v])·bf16(W_ih)^T (fp32 MFMA accum, identical math to the
//   old leaf x-GEMM);  r=sigm(gi_r+bR); z=sigm(gi_z+bZ);
//   n=tanh(gi_n+bN+r*bHn); h=(1-z)*n  -> bf16 (identical rounding).
// grid 782 x 512 (64 vocab rows per block). LDS-routed full-line stores.
// ---------------------------------------------------------------------------
__global__ __launch_bounds__(512, 2) void prep_hleaf(
    const unsigned short* __restrict__ embb,
    const unsigned short* __restrict__ wih,
    const float*          __restrict__ b_ih,
    const float*          __restrict__ b_hh,
    unsigned short*       __restrict__ H)
{
  __shared__ unsigned short lds[64 * 128];
  __shared__ unsigned short hvb[64 * 128];
  const int t = threadIdx.x;
  const int base = blockIdx.x * 64;

  // stage 64 sequential embb rows (XOR-swizzled 16B chunks)
#pragma unroll
  for (int i = 0; i < 2; ++i) {
    int g = t + 512 * i;
    int m = g >> 4, c = g & 15;
    int v = base + m; if (v > 49999) v = 49999;
    uint4 vv = *(const uint4*)(embb + (size_t)v * 128 + c * 8);
    *(uint4*)(lds + m * 128 + ((c ^ (m & 15)) << 3)) = vv;
  }

  const int w = __builtin_amdgcn_readfirstlane(t >> 6);
  const int lane = t & 63, l = lane & 15, q = lane >> 4;
  const int j = w * 16 + l;

  bf16x8 Br[4], Bz[4], Bn[4];
#pragma unroll
  for (int ks = 0; ks < 4; ++ks) {
    const int ko = ks * 32 + q * 8;
    Br[ks] = *(const bf16x8*)(wih + (size_t)j * 128 + ko);
    Bz[ks] = *(const bf16x8*)(wih + (size_t)(128 + j) * 128 + ko);
    Bn[ks] = *(const bf16x8*)(wih + (size_t)(256 + j) * 128 + ko);
  }
  const float bR = b_ih[j] + b_hh[j];
  const float bZ = b_ih[128 + j] + b_hh[128 + j];
  const float bN = b_ih[256 + j];
  const float bH = b_hh[256 + j];

  f32x4 Cr[4] = {{0,0,0,0},{0,0,0,0},{0,0,0,0},{0,0,0,0}};
  f32x4 Cz[4] = {{0,0,0,0},{0,0,0,0},{0,0,0,0},{0,0,0,0}};
  f32x4 Cn[4] = {{0,0,0,0},{0,0,0,0},{0,0,0,0},{0,0,0,0}};
  __syncthreads();

#pragma unroll
  for (int ks = 0; ks < 4; ++ks) {
    bf16x8 A[4];
#pragma unroll
    for (int mt = 0; mt < 4; ++mt) {
      int m = mt * 16 + l, c = ks * 4 + q;
      A[mt] = *(const bf16x8*)(lds + m * 128 + (((c ^ l) & 15) << 3));
    }
#pragma unroll
    for (int mt = 0; mt < 4; ++mt) {
      Cr[mt] = mfma16(A[mt], Br[ks], Cr[mt]);
      Cz[mt] = mfma16(A[mt], Bz[ks], Cz[mt]);
      Cn[mt] = mfma16(A[mt], Bn[ks], Cn[mt]);
    }
  }

#pragma unroll
  for (int mt = 0; mt < 4; ++mt)
#pragma unroll
    for (int e = 0; e < 4; ++e) {
      int b = mt * 16 + q * 4 + e;              // C/D: col=lane&15, row=quad*4+reg
      float r  = sigm(Cr[mt][e] + bR);
      float z  = sigm(Cz[mt][e] + bZ);
      float nv = tanhf_(Cn[mt][e] + bN + r * bH);
      float hv = (1.0f - z) * nv;
      hvb[b * 128 + (j ^ (q << 4))] = f2b(hv);
    }
  __syncthreads();

  // full-line stores
#pragma unroll
  for (int i = 0; i < 2; ++i) {
    int g = t + 512 * i;
    int b = g >> 4, c8 = (g & 15) * 8;
    int qq = (b >> 2) & 3;
    if (base + b < 50000) {
      uint4 v = *(const uint4*)(hvb + b * 128 + (c8 ^ (qq << 4)));
      *(uint4*)(H + (size_t)(base + b) * 128 + c8) = v;
    }
  }
}

// ---------------------------------------------------------------------------
// GRU (levels 5..0): persistent. Wave w owns 16 output cols j=w*16+l.
// A (x||h0) in LDS (XOR-swizzled); hv via separate hvb buffer -> uint4 stores.
// ---------------------------------------------------------------------------
template <bool HAS_H>
__global__ __launch_bounds__(512, 2) void gru_mfma(
    const int*            __restrict__ tok,
    const unsigned short* __restrict__ embb,
    const unsigned short* __restrict__ wih,
    const unsigned short* __restrict__ whh,
    const float*          __restrict__ b_ih,
    const float*          __restrict__ b_hh,
    const unsigned short* __restrict__ h0,
    unsigned short*       __restrict__ hout,
    unsigned*             __restrict__ acc,
    int nNodes, int npb)
{
  constexpr int RS  = HAS_H ? 256 : 128;   // ushorts per LDS row
  constexpr int NKS = HAS_H ? 8 : 4;
  __shared__ unsigned short lds[64 * RS];      // A tile (x || h0)
  __shared__ unsigned short hvb[64 * 128];     // hv staging for full-line store

  const int t = threadIdx.x;
  const int nodeBeg = blockIdx.x * npb;
  const int nodeEnd = min(nNodes, nodeBeg + npb);

  const int w = __builtin_amdgcn_readfirstlane(t >> 6);
  const int lane = t & 63, l = lane & 15, q = lane >> 4;
  const int j = w * 16 + l;

  // per-thread staging coords (2 chunks each for x and h0)
  const int sm0 = t >> 4,          sc0 = t & 15;          // g = t
  const int sm1 = (t + 512) >> 4,  sc1 = (t + 512) & 15;  // g = t + 512

  // B fragments in registers (rows of W are GEMM cols; frag = 8 contig k)
  bf16x8 Br[NKS], Bz[NKS], Bn[4], Bh[HAS_H ? 4 : 1];
#pragma unroll
  for (int ks = 0; ks < 4; ++ks) {
    const int ko = ks * 32 + q * 8;
    Br[ks] = *(const bf16x8*)(wih + (size_t)j * 128 + ko);
    Bz[ks] = *(const bf16x8*)(wih + (size_t)(128 + j) * 128 + ko);
    Bn[ks] = *(const bf16x8*)(wih + (size_t)(256 + j) * 128 + ko);
    if constexpr (HAS_H) {
      Br[4 + ks] = *(const bf16x8*)(whh + (size_t)j * 128 + ko);
      Bz[4 + ks] = *(const bf16x8*)(whh + (size_t)(128 + j) * 128 + ko);
      Bh[ks]     = *(const bf16x8*)(whh + (size_t)(256 + j) * 128 + ko);
    }
  }
  const float bR = b_ih[j] + b_hh[j];
  const float bZ = b_ih[128 + j] + b_hh[128 + j];
  const float bN = b_ih[256 + j];
  const float bH = b_hh[256 + j];

  float mx[4][4];
#pragma unroll
  for (int mt = 0; mt < 4; ++mt)
#pragma unroll
    for (int e = 0; e < 4; ++e) mx[mt][e] = -1e30f;

  // prefetch first node into regs
  uint4 px0, px1, ph0, ph1;
  {
    const int* tp = tok + nodeBeg * 64;
    px0 = *(const uint4*)(embb + (size_t)tp[sm0] * 128 + sc0 * 8);
    px1 = *(const uint4*)(embb + (size_t)tp[sm1] * 128 + sc1 * 8);
    if constexpr (HAS_H) {
      const unsigned short* hp = h0 + (size_t)nodeBeg * 8192;
      ph0 = *(const uint4*)(hp + sm0 * 128 + sc0 * 8);
      ph1 = *(const uint4*)(hp + sm1 * 128 + sc1 * 8);
    }
  }

  for (int node = nodeBeg; node < nodeEnd; ++node) {
    // A-write from prefetch regs (x chunks 0..15, h0 chunks 16..31)
    *(uint4*)(lds + sm0 * RS + ((sc0 ^ (sm0 & 15)) << 3)) = px0;
    *(uint4*)(lds + sm1 * RS + ((sc1 ^ (sm1 & 15)) << 3)) = px1;
    if constexpr (HAS_H) {
      *(uint4*)(lds + sm0 * 256 + ((16 | ((sc0 ^ (sm0 & 15)) & 15)) << 3)) = ph0;
      *(uint4*)(lds + sm1 * 256 + ((16 | ((sc1 ^ (sm1 & 15)) & 15)) << 3)) = ph1;
    }
    __syncthreads();

    // issue next node's loads (latency hidden under MFMA + epilogue)
    if (node + 1 < nodeEnd) {
      const int* tp = tok + (node + 1) * 64;
      px0 = *(const uint4*)(embb + (size_t)tp[sm0] * 128 + sc0 * 8);
      px1 = *(const uint4*)(embb + (size_t)tp[sm1] * 128 + sc1 * 8);
      if constexpr (HAS_H) {
        const unsigned short* hp = h0 + (size_t)(node + 1) * 8192;
        ph0 = *(const uint4*)(hp + sm0 * 128 + sc0 * 8);
        ph1 = *(const uint4*)(hp + sm1 * 128 + sc1 * 8);
      }
    }

    f32x4 Cr[4] = {{0,0,0,0},{0,0,0,0},{0,0,0,0},{0,0,0,0}};
    f32x4 Cz[4] = {{0,0,0,0},{0,0,0,0},{0,0,0,0},{0,0,0,0}};
    f32x4 Cn[4] = {{0,0,0,0},{0,0,0,0},{0,0,0,0},{0,0,0,0}};
    f32x4 Ch[4] = {{0,0,0,0},{0,0,0,0},{0,0,0,0},{0,0,0,0}};

#pragma unroll
    for (int ks = 0; ks < NKS; ++ks) {
      bf16x8 A[4];
#pragma unroll
      for (int mt = 0; mt < 4; ++mt) {
        int m = mt * 16 + l;
        int c = ks * 4 + q;
        A[mt] = *(const bf16x8*)(lds + m * RS + (((c & 16) | ((c ^ l) & 15)) << 3));
      }
#pragma unroll
      for (int mt = 0; mt < 4; ++mt) {
        Cr[mt] = mfma16(A[mt], Br[ks], Cr[mt]);
        Cz[mt] = mfma16(A[mt], Bz[ks], Cz[mt]);
        if (!HAS_H || ks < 4) Cn[mt] = mfma16(A[mt], Bn[ks & 3], Cn[mt]);
        else                  Ch[mt] = mfma16(A[mt], Bh[ks - 4], Ch[mt]);
      }
    }

    // gates in-register; hv -> hvb (q-swizzled cols); running max in regs
#pragma unroll
    for (int mt = 0; mt < 4; ++mt) {
#pragma unroll
      for (int e = 0; e < 4; ++e) {
        const int b = mt * 16 + q * 4 + e;      // C/D: col=lane&15, row=quad*4+reg
        float r  = sigm(Cr[mt][e] + bR);
        float z  = sigm(Cz[mt][e] + bZ);
        float hn_ = bH + (HAS_H ? Ch[mt][e] : 0.0f);
        float nv = tanhf_(Cn[mt][e] + bN + r * hn_);
        float hp = 0.0f;
        if constexpr (HAS_H) {
          int c16 = j >> 3;
          hp = b2f(lds[b * 256 + ((16 | ((c16 ^ (b & 15)) & 15)) << 3) + (j & 7)]);
        }
        float hv = (1.0f - z) * nv + z * hp;
        hvb[b * 128 + (j ^ (q << 4))] = f2b(hv);
        mx[mt][e] = fmaxf(mx[mt][e], hv);
      }
    }
    __syncthreads();   // A reads + hvb writes done

    // coalesced full-line hout store (reads hvb only; next A-write is disjoint)
    unsigned short* ho = hout + (size_t)node * 8192;
    {
      int b0 = sm0, c80 = sc0 * 8, q0 = (b0 >> 2) & 3;
      int b1 = sm1, c81 = sc1 * 8, q1 = (b1 >> 2) & 3;
      uint4 v0 = *(const uint4*)(hvb + b0 * 128 + (c80 ^ (q0 << 4)));
      uint4 v1 = *(const uint4*)(hvb + b1 * 128 + (c81 ^ (q1 << 4)));
      *(uint4*)(ho + b0 * 128 + c80) = v0;
      *(uint4*)(ho + b1 * 128 + c81) = v1;
    }
  }

  // one atomic set per block, at true kernel end (no barrier after)
  unsigned* accs = acc + (blockIdx.x & 31) * 8192;
#pragma unroll
  for (int mt = 0; mt < 4; ++mt)
#pragma unroll
    for (int e = 0; e < 4; ++e) {
      const int b = mt * 16 + q * 4 + e;
      atomicMax(accs + b * 128 + j, fenc(mx[mt][e]));
    }
}

// ---------------------------------------------------------------------------
// Attention: grid n (parents), block 512 (8 waves: wm=row-half, wn=col-chunk32).
// LEAF variant: child rows gathered straight from H_leaf via tokens
// (row m of parent p is token tok6[p*256+m]); also computes the leaf max
// from the staged LDS tile. Max atomics are LANE-CONTIGUOUS (word = t+512e)
// so the RMW traffic is 4 B/lane, not 32 B/lane. Atomics at true kernel end.
// ---------------------------------------------------------------------------
template <bool LEAF>
__global__ __launch_bounds__(512, 2) void attn_mfma(
    const unsigned short* __restrict__ hch,   // child h (non-leaf), rows p*256..
    const unsigned short* __restrict__ swt,   // 128x128 bf16 [k_u][h]
    const float*          __restrict__ sb,
    const float*          __restrict__ ctx,
    unsigned short*       __restrict__ h0out,
    const int*            __restrict__ tok6,  // LEAF only
    const unsigned short* __restrict__ hleaf, // LEAF only
    unsigned*             __restrict__ acc)   // LEAF only
{
  __shared__ unsigned short chs[256 * 128];   // 64 KB, swizzled
  __shared__ float spart[4][256];
  __shared__ float alf[256];

  const int p = blockIdx.x;
  const int t = threadIdx.x;

  if constexpr (LEAF) {
    const int* tokp = tok6 + p * 256;
#pragma unroll
    for (int i = 0; i < 8; ++i) {
      int g = t + 512 * i;                    // 0..4095 16B-chunks
      int m = g >> 4, c = g & 15;
      int tv = tokp[m];
      uint4 v = *(const uint4*)(hleaf + (size_t)tv * 128 + c * 8);
      *(uint4*)(chs + m * 128 + ((c ^ (m & 15)) << 3)) = v;
    }
  } else {
    const unsigned short* src = hch + (size_t)p * 256 * 128;
#pragma unroll
    for (int i = 0; i < 8; ++i) {
      int g = t + 512 * i;                    // 0..4095 16B-chunks
      int m = g >> 4, c = g & 15;
      uint4 v = *(const uint4*)(src + m * 128 + c * 8);
      *(uint4*)(chs + m * 128 + ((c ^ (m & 15)) << 3)) = v;
    }
  }

  const int w = __builtin_amdgcn_readfirstlane(t >> 6);
  const int wm = w >> 2, wn = w & 3;
  const int lane = t & 63, l = lane & 15, q = lane >> 4;

  bf16x8 Bs[2][4];
#pragma unroll
  for (int nt = 0; nt < 2; ++nt)
#pragma unroll
    for (int ks = 0; ks < 4; ++ks)
      Bs[nt][ks] = *(const bf16x8*)(swt + (size_t)(wn * 32 + nt * 16 + l) * 128 + ks * 32 + q * 8);

  f32x4 Cu[8][2] = {};
  __syncthreads();

#pragma unroll
  for (int ks = 0; ks < 4; ++ks) {
#pragma unroll
    for (int mt = 0; mt < 8; ++mt) {
      int m = wm * 128 + mt * 16 + l;
      int c = ks * 4 + q;
      bf16x8 A = *(const bf16x8*)(chs + m * 128 + (((c ^ (m & 15)) & 15) << 3));
      Cu[mt][0] = mfma16(A, Bs[0][ks], Cu[mt][0]);
      Cu[mt][1] = mfma16(A, Bs[1][ks], Cu[mt][1]);
    }
  }

  const float sb0 = sb[wn * 32 + l],  sb1 = sb[wn * 32 + 16 + l];
  const float cx0 = ctx[wn * 32 + l], cx1 = ctx[wn * 32 + 16 + l];
#pragma unroll
  for (int mt = 0; mt < 8; ++mt) {
    float pe[4];
#pragma unroll
    for (int e = 0; e < 4; ++e)
      pe[e] = tanhf_(Cu[mt][0][e] + sb0) * cx0 + tanhf_(Cu[mt][1][e] + sb1) * cx1;
#pragma unroll
    for (int mask = 1; mask < 16; mask <<= 1)
#pragma unroll
      for (int e = 0; e < 4; ++e)
        pe[e] += __shfl_xor(pe[e], mask, 16);
    if (l == 0) {
      int r = wm * 128 + mt * 16 + q * 4;
#pragma unroll
      for (int e = 0; e < 4; ++e) spart[wn][r + e] = pe[e];
    }
  }
  __syncthreads();

  if (t < 256) {
    float s = tanhf_(spart[0][t] + spart[1][t] + spart[2][t] + spart[3][t]);
    spart[0][t] = s;                          // reuse row 0 as s-values
  }
  __syncthreads();
  if (t < 64) {
    float s0 = spart[0][t], s1 = spart[0][64 + t], s2 = spart[0][128 + t], s3 = spart[0][192 + t];
    float m = fmaxf(fmaxf(s0, s1), fmaxf(s2, s3));
    float e0 = __expf(s0 - m), e1 = __expf(s1 - m), e2 = __expf(s2 - m), e3 = __expf(s3 - m);
    float inv = 1.0f / (e0 + e1 + e2 + e3);
    alf[t] = e0 * inv; alf[64 + t] = e1 * inv; alf[128 + t] = e2 * inv; alf[192 + t] = e3 * inv;
  }
  __syncthreads();

#pragma unroll
  for (int i = 0; i < 2; ++i) {
    int id = t + 512 * i;                     // 0..1023: (b, chunk)
    int b = id >> 4, c = id & 15;
    float o[8] = {0,0,0,0,0,0,0,0};
#pragma unroll
    for (int a = 0; a < 4; ++a) {
      int m = a * 64 + b;
      const unsigned short* rp = chs + m * 128 + ((c ^ (m & 15)) << 3);
      float al = alf[a * 64 + b];
#pragma unroll
      for (int k = 0; k < 8; ++k) o[k] += al * b2f(rp[k]);
    }
    ushort4 o0, o1;
    o0.x = f2b(o[0]); o0.y = f2b(o[1]); o0.z = f2b(o[2]); o0.w = f2b(o[3]);
    o1.x = f2b(o[4]); o1.y = f2b(o[5]); o1.z = f2b(o[6]); o1.w = f2b(o[7]);
    *(ushort4*)(h0out + (size_t)(p * 64 + b) * 128 + c * 8)     = o0;
    *(ushort4*)(h0out + (size_t)(p * 64 + b) * 128 + c * 8 + 4) = o1;
  }

  if constexpr (LEAF) {
    // leaf-level max from the staged tile, LANE-CONTIGUOUS acc mapping:
    // thread t owns acc words {t + 512*e}: j = t&127 (fixed), b = (t>>7)+4e.
    const int jj = t & 127;
    const int c  = jj >> 3;
    float mxv[16];
#pragma unroll
    for (int e = 0; e < 16; ++e) mxv[e] = -1e30f;
#pragma unroll
    for (int a = 0; a < 4; ++a) {
#pragma unroll
      for (int e = 0; e < 16; ++e) {
        int b = (t >> 7) + 4 * e;
        int m = a * 64 + b;
        float v = b2f(chs[m * 128 + (((c ^ (m & 15)) & 15) << 3) + (jj & 7)]);
        mxv[e] = fmaxf(mxv[e], v);
      }
    }
    unsigned* accs = acc + (p & 31) * 8192;
#pragma unroll
    for (int e = 0; e < 16; ++e)
      atomicMax(accs + t + 512 * e, fenc(mxv[e]));
  }
}

extern "C" void kernel_launch(void* const* d_in, const int* in_sizes, int n_in,
                              void* d_out, int out_size, void* d_ws, size_t ws_size,
                              hipStream_t stream) {
  const int*   tokens = (const int*)d_in[0];
  const float* emb    = (const float*)d_in[1];
  const float* sent_w = (const float*)d_in[2];
  const float* sent_b = (const float*)d_in[3];
  const float* ctx_w  = (const float*)d_in[4];
  const float* w_ih   = (const float*)d_in[5];
  const float* w_hh   = (const float*)d_in[6];
  const float* b_ih   = (const float*)d_in[7];
  const float* b_hh   = (const float*)d_in[8];

  char* ws = (char*)d_ws;
  unsigned*       acc  = (unsigned*)(ws + WS_ACC);
  unsigned short* wihb = (unsigned short*)(ws + WS_WIH);
  unsigned short* whhb = (unsigned short*)(ws + WS_WHH);
  unsigned short* swtb = (unsigned short*)(ws + WS_SWT);
  unsigned short* embb = (unsigned short*)(ws + WS_EMBB);
  unsigned short* hlf  = (unsigned short*)(ws + WS_HLEAF);
  unsigned short* hA   = (unsigned short*)(ws + WS_HA);
  unsigned short* hB   = (unsigned short*)(ws + WS_HB);
  unsigned short* h0b  = (unsigned short*)(ws + WS_H0);

  hipLaunchKernelGGL(prep_all, dim3(7722), dim3(256), 0, stream,
                     emb, w_ih, w_hh, sent_w, embb, wihb, whhb, swtb, acc);
  hipLaunchKernelGGL(prep_hleaf, dim3(782), dim3(512), 0, stream,
                     embb, wihb, b_ih, b_hh, hlf);

  static const int offs[7] = {0, 1, 5, 21, 85, 341, 1365};
  const int* tok6 = tokens + (size_t)1365 * 64;

  for (int d = 5; d >= 0; --d) {
    int n = 1 << (2 * d);
    int off = offs[d];
    int npb  = (n + 511) / 512;                  // nodes per block
    int grid = (n + npb - 1) / npb;              // <=512, balanced chunks
    unsigned short* hout  = (d & 1) ? hB : hA;
    unsigned short* child = (d & 1) ? hA : hB;   // level d+1 output (non-leaf)
    if (d == 5) {
      hipLaunchKernelGGL((attn_mfma<true>), dim3(n), dim3(512), 0, stream,
                         (const unsigned short*)nullptr, swtb, sent_b, ctx_w,
                         h0b, tok6, hlf, acc);
    } else {
      hipLaunchKernelGGL((attn_mfma<false>), dim3(n), dim3(512), 0, stream,
                         child, swtb, sent_b, ctx_w, h0b,
                         (const int*)nullptr, (const unsigned short*)nullptr,
                         (unsigned*)nullptr);
    }
    hipLaunchKernelGGL((gru_mfma<true>), dim3(grid), dim3(512), 0, stream,
                       tokens + (size_t)off * 64, embb, wihb, whhb, b_ih, b_hh,
                       h0b, hout, acc, n, npb);
  }
  hipLaunchKernelGGL(decode_out, dim3(32), dim3(256), 0, stream, acc, (float*)d_out);
}